// Round 2
// baseline (2931.800 us; speedup 1.0000x reference)
//
#include <hip/hip_runtime.h>

#define DEV __device__ __forceinline__

typedef __bf16 bf16x8 __attribute__((ext_vector_type(8)));
typedef float  f32x4  __attribute__((ext_vector_type(4)));

typedef const __attribute__((address_space(1))) unsigned int* gas_ptr;
typedef       __attribute__((address_space(3))) unsigned int* las_ptr;

DEV unsigned short f2bf(float f) {
  union { __bf16 h; unsigned short u; } c; c.h = (__bf16)f; return c.u;
}

DEV void gll16(const void* g, void* l) {
  __builtin_amdgcn_global_load_lds((gas_ptr)g, (las_ptr)l, 16, 0, 0);
}

DEV f32x4 mfma16(bf16x8 a, bf16x8 b, f32x4 c) {
  return __builtin_amdgcn_mfma_f32_16x16x32_bf16(a, b, c, 0, 0, 0);
}

// ---------------------------------------------------------------------------
// Transpose + f32->bf16 convert: src [K,N] f32 -> dst [N,K] bf16. grid.z = layer.
__global__ __launch_bounds__(256)
void tcvt_k(const float* __restrict__ src, unsigned short* __restrict__ dst,
            int K, int N)
{
  __shared__ float t[32][33];
  const int tx = threadIdx.x, ty = threadIdx.y;
  const size_t mo = (size_t)blockIdx.z * K * N;
  const int n0 = blockIdx.x * 32, k0 = blockIdx.y * 32;
  const float* s = src + mo;
  unsigned short* d = dst + mo;
#pragma unroll
  for (int i = 0; i < 4; i++)
    t[ty + i*8][tx] = s[(size_t)(k0 + ty + i*8) * N + n0 + tx];
  __syncthreads();
#pragma unroll
  for (int i = 0; i < 4; i++)
    d[(size_t)(n0 + ty + i*8) * K + k0 + tx] = f2bf(t[tx][ty + i*8]);
}

// ---------------------------------------------------------------------------
// Embedding: x[row] = tok_emb[tok[row]] + pos_emb[row % 1024]
__global__ __launch_bounds__(256)
void embed_k(const int* __restrict__ toks, const float* __restrict__ te,
             const float* __restrict__ pe, float* __restrict__ x)
{
  const int row = blockIdx.x, t = threadIdx.x;
  const int tok = toks[row], s = row & 1023;
  float4 a = ((const float4*)(te + (size_t)tok * 1024))[t];
  float4 p = ((const float4*)(pe + (size_t)s   * 1024))[t];
  float4 o; o.x = a.x+p.x; o.y = a.y+p.y; o.z = a.z+p.z; o.w = a.w+p.w;
  ((float4*)(x + (size_t)row * 1024))[t] = o;
}

// ---------------------------------------------------------------------------
// LayerNorm over D=1024, f32 in -> bf16 out. One block (256 thr) per row.
__global__ __launch_bounds__(256)
void ln_k(const float* __restrict__ x, const float* __restrict__ g,
          const float* __restrict__ bta, unsigned short* __restrict__ h)
{
  __shared__ float red[8];
  const int row = blockIdx.x, t = threadIdx.x;
  const float4 v = ((const float4*)(x + (size_t)row * 1024))[t];
  float s  = v.x + v.y + v.z + v.w;
  float sq = v.x*v.x + v.y*v.y + v.z*v.z + v.w*v.w;
#pragma unroll
  for (int mk = 32; mk >= 1; mk >>= 1) {
    s  += __shfl_xor(s,  mk);
    sq += __shfl_xor(sq, mk);
  }
  const int wv = t >> 6;
  if ((t & 63) == 0) { red[wv] = s; red[4 + wv] = sq; }
  __syncthreads();
  s  = red[0] + red[1] + red[2] + red[3];
  sq = red[4] + red[5] + red[6] + red[7];
  const float mu = s * (1.f/1024.f);
  const float rs = rsqrtf(sq * (1.f/1024.f) - mu*mu + 1e-5f);
  const float4 gv = ((const float4*)g)[t];
  const float4 bv = ((const float4*)bta)[t];
  ushort4 o;
  o.x = f2bf((v.x - mu) * rs * gv.x + bv.x);
  o.y = f2bf((v.y - mu) * rs * gv.y + bv.y);
  o.z = f2bf((v.z - mu) * rs * gv.z + bv.z);
  o.w = f2bf((v.w - mu) * rs * gv.w + bv.w);
  ((ushort4*)(h + (size_t)row * 1024))[t] = o;
}

// ---------------------------------------------------------------------------
// bf16 GEMM, m97 structure: C[M,N] = A[M,K] @ Bt[N,K]^T.
// 128x128 tile, BK=32, 256 threads (4 waves 2x2), wave tile 64x64, acc 4x4.
// Per K-step: 4x global_load_lds(16B), 8x ds_read_b128/wave, 16 MFMA/wave.
// EPI: 0 = QKV scatter (z selects Wq/Wk/Wv; q scaled 0.125; v transposed)
//      1 = residual: xio[r,c] += acc + bias[c]
//      2 = relu(acc + bias) -> bf16 o0
//      3 = acc + bias -> f32 xio
template<int EPI>
__global__ __launch_bounds__(256)
void gemm_k(const unsigned short* __restrict__ A,
            const unsigned short* __restrict__ B0,
            const unsigned short* __restrict__ B1,
            const unsigned short* __restrict__ B2,
            const float* __restrict__ bias,
            float* __restrict__ xio,
            unsigned short* __restrict__ o0,
            unsigned short* __restrict__ o1,
            unsigned short* __restrict__ o2,
            int K, int N)
{
  __shared__ __align__(16) unsigned short As[128 * 32];
  __shared__ __align__(16) unsigned short Bs[128 * 32];
  const int tid = threadIdx.x;
  const int wave = tid >> 6, lane = tid & 63;
  const int wm = wave >> 1, wn = wave & 1;
  const int m0 = blockIdx.x * 128, n0 = blockIdx.y * 128;
  const int r16 = lane & 15, r4 = lane >> 4;

  const unsigned short* Bt = B0;
  if (EPI == 0) Bt = (blockIdx.z == 0) ? B0 : (blockIdx.z == 1) ? B1 : B2;

  // staging addresses: thread t covers row tid>>2 (0..63), 8-short chunk tid&3
  const unsigned short* ga = A  + (size_t)(m0 + (tid >> 2)) * K + (tid & 3) * 8;
  const unsigned short* gb = Bt + (size_t)(n0 + (tid >> 2)) * K + (tid & 3) * 8;
  const size_t rstep = (size_t)64 * K;
  unsigned short* la = As + wave * 512;   // wave-uniform base, 16 rows/wave
  unsigned short* lb = Bs + wave * 512;

  f32x4 acc[4][4] = {};

  for (int kt = 0; kt < K; kt += 32) {
    __syncthreads();                      // prev tile LDS reads done
    gll16(ga,         la);
    gll16(ga + rstep, la + 2048);
    gll16(gb,         lb);
    gll16(gb + rstep, lb + 2048);
    ga += 32; gb += 32;
    __syncthreads();                      // drains vmcnt -> staging visible
    bf16x8 av[4], bv[4];
#pragma unroll
    for (int mf = 0; mf < 4; mf++)
      av[mf] = *(const bf16x8*)&As[(wm*64 + mf*16 + r16) * 32 + r4 * 8];
#pragma unroll
    for (int nf = 0; nf < 4; nf++)
      bv[nf] = *(const bf16x8*)&Bs[(wn*64 + nf*16 + r16) * 32 + r4 * 8];
#pragma unroll
    for (int mf = 0; mf < 4; mf++)
#pragma unroll
      for (int nf = 0; nf < 4; nf++)
        acc[mf][nf] = mfma16(av[mf], bv[nf], acc[mf][nf]);
  }

  const int row0 = m0 + wm * 64, col0 = n0 + wn * 64;
#pragma unroll
  for (int mf = 0; mf < 4; mf++) {
#pragma unroll
    for (int nf = 0; nf < 4; nf++) {
#pragma unroll
      for (int jj = 0; jj < 4; jj++) {
        const int r = row0 + mf*16 + r4*4 + jj;
        const int c = col0 + nf*16 + r16;
        const float v = acc[mf][nf][jj];
        if (EPI == 0) {
          const int z = blockIdx.z;
          const int b_ = r >> 10, s_ = r & 1023;
          const int hh = c >> 6, e = c & 63;
          if (z == 0)
            o0[((size_t)(b_*16 + hh) * 1024 + s_) * 64 + e] = f2bf(v * 0.125f);
          else if (z == 1)
            o1[((size_t)(b_*16 + hh) * 1024 + s_) * 64 + e] = f2bf(v);
          else
            o2[((size_t)(b_*16 + hh) * 64 + e) * 1024 + s_] = f2bf(v);
        } else if (EPI == 1) {
          const size_t idx = (size_t)r * N + c;
          xio[idx] += v + bias[c];
        } else if (EPI == 2) {
          const float t = v + bias[c];
          o0[(size_t)r * N + c] = f2bf(t > 0.f ? t : 0.f);
        } else {
          xio[(size_t)r * N + c] = v + bias[c];
        }
      }
    }
  }
}

// ---------------------------------------------------------------------------
// Flash attention. Grid (8 q-tiles, 16 heads, 4 batch), 256 threads (4 waves).
// q: [B,H,S,64] bf16 (pre-scaled by 0.125), k: [B,H,S,64], vT: [B,H,64,S].
// Each wave owns 32 q rows; KV tiles of 64; online softmax; out att [B*S, D].
__global__ __launch_bounds__(256)
void attn_k(const unsigned short* __restrict__ qb,
            const unsigned short* __restrict__ kb,
            const unsigned short* __restrict__ vtb,
            unsigned short* __restrict__ att)
{
  __shared__ __align__(16) unsigned short Ks[64 * 64];   // [kv][e]
  __shared__ __align__(16) unsigned short Vs[64 * 64];   // [e][kv]
  __shared__ __align__(16) unsigned short Ps[128 * 64];  // [q_local][kv]
  const int qt = blockIdx.x, h = blockIdx.y, b = blockIdx.z;
  const int tid = threadIdx.x, wave = tid >> 6, lane = tid & 63;
  const int r16 = lane & 15, r4 = lane >> 4;
  const int q0 = qt * 128;
  const size_t bh = (size_t)(b * 16 + h);
  const unsigned short* qbh = qb  + bh * 1024 * 64;
  const unsigned short* kbh = kb  + bh * 1024 * 64;
  const unsigned short* vbh = vtb + bh * 64 * 1024;

  bf16x8 qf[2][2];
#pragma unroll
  for (int mf = 0; mf < 2; mf++)
#pragma unroll
    for (int kc = 0; kc < 2; kc++)
      qf[mf][kc] = *(const bf16x8*)&qbh[(size_t)(q0 + wave*32 + mf*16 + r16) * 64 + kc*32 + r4*8];

  f32x4 oacc[2][4] = {};
  float m_i[2][4], l_i[2][4];
#pragma unroll
  for (int mf = 0; mf < 2; mf++)
#pragma unroll
    for (int jj = 0; jj < 4; jj++) { m_i[mf][jj] = -INFINITY; l_i[mf][jj] = 0.f; }

  const int ntiles = q0 / 64 + 2;   // kv tiles covering kv <= q0+127
  for (int t = 0; t < ntiles; t++) {
    const int kv0 = t * 64;
    __syncthreads();                // prev tile reads done
#pragma unroll
    for (int cc = 0; cc < 2; cc++) {
      const int chunk = wave * 2 + cc;
      gll16(kbh + (size_t)(kv0 + chunk*8 + (lane >> 3)) * 64 + (lane & 7) * 8,
            Ks + chunk * 512);
      gll16(vbh + (size_t)(chunk*8 + (lane >> 3)) * 1024 + kv0 + (lane & 7) * 8,
            Vs + chunk * 512);
    }
    __syncthreads();                // staging complete

    // QK^T
    f32x4 sacc[2][4] = {};
#pragma unroll
    for (int kc = 0; kc < 2; kc++) {
#pragma unroll
      for (int nf = 0; nf < 4; nf++) {
        bf16x8 kf = *(const bf16x8*)&Ks[(nf*16 + r16) * 64 + kc*32 + r4*8];
#pragma unroll
        for (int mf = 0; mf < 2; mf++)
          sacc[mf][nf] = mfma16(qf[mf][kc], kf, sacc[mf][nf]);
      }
    }

    // online softmax (per row = (mf, jj); cols spread over 16-lane group x 4 nf)
#pragma unroll
    for (int mf = 0; mf < 2; mf++) {
#pragma unroll
      for (int jj = 0; jj < 4; jj++) {
        const int qrow = q0 + wave*32 + mf*16 + r4*4 + jj;
        float vv[4];
#pragma unroll
        for (int nf = 0; nf < 4; nf++) {
          const int col = kv0 + nf*16 + r16;
          vv[nf] = (col <= qrow) ? sacc[mf][nf][jj] : -1e30f;
        }
        float rmax = fmaxf(fmaxf(vv[0], vv[1]), fmaxf(vv[2], vv[3]));
#pragma unroll
        for (int mk = 8; mk >= 1; mk >>= 1) rmax = fmaxf(rmax, __shfl_xor(rmax, mk));
        const float mnew = fmaxf(m_i[mf][jj], rmax);
        const float corr = __expf(m_i[mf][jj] - mnew);   // first tile: exp(-inf)=0
        float pv[4], ps = 0.f;
#pragma unroll
        for (int nf = 0; nf < 4; nf++) { pv[nf] = __expf(vv[nf] - mnew); ps += pv[nf]; }
#pragma unroll
        for (int mk = 8; mk >= 1; mk >>= 1) ps += __shfl_xor(ps, mk);
        l_i[mf][jj] = l_i[mf][jj] * corr + ps;
        m_i[mf][jj] = mnew;
#pragma unroll
        for (int nh = 0; nh < 4; nh++) oacc[mf][nh][jj] *= corr;
#pragma unroll
        for (int nf = 0; nf < 4; nf++)
          Ps[(wave*32 + mf*16 + r4*4 + jj) * 64 + nf*16 + r16] = f2bf(pv[nf]);
      }
    }
    __syncthreads();                // P visible (safety)

    // PV
#pragma unroll
    for (int kc = 0; kc < 2; kc++) {
#pragma unroll
      for (int mf = 0; mf < 2; mf++) {
        bf16x8 pf = *(const bf16x8*)&Ps[(wave*32 + mf*16 + r16) * 64 + kc*32 + r4*8];
#pragma unroll
        for (int nh = 0; nh < 4; nh++) {
          bf16x8 vf = *(const bf16x8*)&Vs[(nh*16 + r16) * 64 + kc*32 + r4*8];
          oacc[mf][nh] = mfma16(pf, vf, oacc[mf][nh]);
        }
      }
    }
  }

  // finalize + write att [B*S, D], col = h*64 + e
#pragma unroll
  for (int mf = 0; mf < 2; mf++) {
#pragma unroll
    for (int nh = 0; nh < 4; nh++) {
#pragma unroll
      for (int jj = 0; jj < 4; jj++) {
        const int row = q0 + wave*32 + mf*16 + r4*4 + jj;
        const int col = nh*16 + r16;
        const float o = oacc[mf][nh][jj] / l_i[mf][jj];
        att[(size_t)(b * 1024 + row) * 1024 + h*64 + col] = f2bf(o);
      }
    }
  }
}

// ---------------------------------------------------------------------------
extern "C" void kernel_launch(void* const* d_in, const int* in_sizes, int n_in,
                              void* d_out, int out_size, void* d_ws, size_t ws_size,
                              hipStream_t stream)
{
  const int*   toks    = (const int*)  d_in[0];
  const float* tok_emb = (const float*)d_in[1];
  const float* pos_emb = (const float*)d_in[2];
  const float* Wq      = (const float*)d_in[3];
  const float* Wk      = (const float*)d_in[4];
  const float* Wv      = (const float*)d_in[5];
  const float* Wo      = (const float*)d_in[6];
  const float* bo      = (const float*)d_in[7];
  const float* ln1_g   = (const float*)d_in[8];
  const float* ln1_b   = (const float*)d_in[9];
  const float* ln2_g   = (const float*)d_in[10];
  const float* ln2_b   = (const float*)d_in[11];
  const float* W1      = (const float*)d_in[12];
  const float* b1      = (const float*)d_in[13];
  const float* W2      = (const float*)d_in[14];
  const float* b2      = (const float*)d_in[15];
  const float* lnf_g   = (const float*)d_in[16];
  const float* lnf_b   = (const float*)d_in[17];
  const float* Wout    = (const float*)d_in[18];
  const float* bout    = (const float*)d_in[19];
  float* out = (float*)d_out;

  char* w = (char*)d_ws;
  size_t off = 0;
  auto alloc = [&](size_t bytes) -> void* {
    void* p = w + off; off += (bytes + 255) & ~(size_t)255; return p;
  };
  unsigned short* wqT   = (unsigned short*)alloc(8ull*1024*1024*2);
  unsigned short* wkT   = (unsigned short*)alloc(8ull*1024*1024*2);
  unsigned short* wvT   = (unsigned short*)alloc(8ull*1024*1024*2);
  unsigned short* woT   = (unsigned short*)alloc(8ull*1024*1024*2);
  unsigned short* w1T   = (unsigned short*)alloc(8ull*1024*4096*2);
  unsigned short* w2T   = (unsigned short*)alloc(8ull*4096*1024*2);
  unsigned short* woutT = (unsigned short*)alloc(256ull*1024*2);
  float*          x     = (float*)         alloc(4096ull*1024*4);
  unsigned short* hbuf  = (unsigned short*)alloc(4096ull*1024*2);
  unsigned short* qbuf  = (unsigned short*)alloc(64ull*1024*64*2);
  unsigned short* kbuf  = (unsigned short*)alloc(64ull*1024*64*2);
  unsigned short* vtb   = (unsigned short*)alloc(64ull*1024*64*2);
  unsigned short* att   = (unsigned short*)alloc(4096ull*1024*2);
  unsigned short* ff    = (unsigned short*)alloc(4096ull*4096*2);
  (void)ws_size; (void)in_sizes; (void)n_in; (void)out_size;

  dim3 tb(32, 8);
  tcvt_k<<<dim3(32, 32, 8),  tb, 0, stream>>>(Wq,   wqT,   1024, 1024);
  tcvt_k<<<dim3(32, 32, 8),  tb, 0, stream>>>(Wk,   wkT,   1024, 1024);
  tcvt_k<<<dim3(32, 32, 8),  tb, 0, stream>>>(Wv,   wvT,   1024, 1024);
  tcvt_k<<<dim3(32, 32, 8),  tb, 0, stream>>>(Wo,   woT,   1024, 1024);
  tcvt_k<<<dim3(128, 32, 8), tb, 0, stream>>>(W1,   w1T,   1024, 4096);
  tcvt_k<<<dim3(32, 128, 8), tb, 0, stream>>>(W2,   w2T,   4096, 1024);
  tcvt_k<<<dim3(8, 32, 1),   tb, 0, stream>>>(Wout, woutT, 1024, 256);

  embed_k<<<4096, 256, 0, stream>>>(toks, tok_emb, pos_emb, x);

  for (int l = 0; l < 8; l++) {
    ln_k<<<4096, 256, 0, stream>>>(x, ln1_g + l*1024, ln1_b + l*1024, hbuf);
    gemm_k<0><<<dim3(32, 8, 3), 256, 0, stream>>>(hbuf,
        wqT + (size_t)l*1048576, wkT + (size_t)l*1048576, wvT + (size_t)l*1048576,
        nullptr, nullptr, qbuf, kbuf, vtb, 1024, 1024);
    attn_k<<<dim3(8, 16, 4), 256, 0, stream>>>(qbuf, kbuf, vtb, att);
    gemm_k<1><<<dim3(32, 8), 256, 0, stream>>>(att,
        woT + (size_t)l*1048576, nullptr, nullptr,
        bo + l*1024, x, nullptr, nullptr, nullptr, 1024, 1024);
    ln_k<<<4096, 256, 0, stream>>>(x, ln2_g + l*1024, ln2_b + l*1024, hbuf);
    gemm_k<2><<<dim3(32, 32), 256, 0, stream>>>(hbuf,
        w1T + (size_t)l*4194304, nullptr, nullptr,
        b1 + l*4096, nullptr, ff, nullptr, nullptr, 1024, 4096);
    gemm_k<1><<<dim3(32, 8), 256, 0, stream>>>(ff,
        w2T + (size_t)l*4194304, nullptr, nullptr,
        b2 + l*1024, x, nullptr, nullptr, nullptr, 4096, 1024);
  }

  ln_k<<<4096, 256, 0, stream>>>(x, lnf_g, lnf_b, hbuf);
  gemm_k<3><<<dim3(32, 2), 256, 0, stream>>>(hbuf, woutT, nullptr, nullptr,
      bout, out, nullptr, nullptr, nullptr, 1024, 256);
}

// Round 3
// 2553.544 us; speedup vs baseline: 1.1481x; 1.1481x over previous
//
#include <hip/hip_runtime.h>

#define DEV __device__ __forceinline__

typedef __bf16 bf16x8 __attribute__((ext_vector_type(8)));
typedef float  f32x4  __attribute__((ext_vector_type(4)));

typedef const __attribute__((address_space(1))) unsigned int* gas_ptr;
typedef       __attribute__((address_space(3))) unsigned int* las_ptr;

DEV unsigned short f2bf(float f) {
  union { __bf16 h; unsigned short u; } c; c.h = (__bf16)f; return c.u;
}

DEV void gll16(const void* g, void* l) {
  __builtin_amdgcn_global_load_lds((gas_ptr)g, (las_ptr)l, 16, 0, 0);
}

DEV f32x4 mfma16(bf16x8 a, bf16x8 b, f32x4 c) {
  return __builtin_amdgcn_mfma_f32_16x16x32_bf16(a, b, c, 0, 0, 0);
}

// ---------------------------------------------------------------------------
// Transpose + f32->bf16 convert: src [K,N] f32 -> dst [N,K] bf16. grid.z = layer.
__global__ __launch_bounds__(256)
void tcvt_k(const float* __restrict__ src, unsigned short* __restrict__ dst,
            int K, int N)
{
  __shared__ float t[32][33];
  const int tx = threadIdx.x, ty = threadIdx.y;
  const size_t mo = (size_t)blockIdx.z * K * N;
  const int n0 = blockIdx.x * 32, k0 = blockIdx.y * 32;
  const float* s = src + mo;
  unsigned short* d = dst + mo;
#pragma unroll
  for (int i = 0; i < 4; i++)
    t[ty + i*8][tx] = s[(size_t)(k0 + ty + i*8) * N + n0 + tx];
  __syncthreads();
#pragma unroll
  for (int i = 0; i < 4; i++)
    d[(size_t)(n0 + ty + i*8) * K + k0 + tx] = f2bf(t[tx][ty + i*8]);
}

// ---------------------------------------------------------------------------
// Embedding: x[row] = tok_emb[tok[row]] + pos_emb[row % 1024]
__global__ __launch_bounds__(256)
void embed_k(const int* __restrict__ toks, const float* __restrict__ te,
             const float* __restrict__ pe, float* __restrict__ x)
{
  const int row = blockIdx.x, t = threadIdx.x;
  const int tok = toks[row], s = row & 1023;
  float4 a = ((const float4*)(te + (size_t)tok * 1024))[t];
  float4 p = ((const float4*)(pe + (size_t)s   * 1024))[t];
  float4 o; o.x = a.x+p.x; o.y = a.y+p.y; o.z = a.z+p.z; o.w = a.w+p.w;
  ((float4*)(x + (size_t)row * 1024))[t] = o;
}

// ---------------------------------------------------------------------------
// LayerNorm over D=1024, f32 in -> bf16 out. One block (256 thr) per row.
__global__ __launch_bounds__(256)
void ln_k(const float* __restrict__ x, const float* __restrict__ g,
          const float* __restrict__ bta, unsigned short* __restrict__ h)
{
  __shared__ float red[8];
  const int row = blockIdx.x, t = threadIdx.x;
  const float4 v = ((const float4*)(x + (size_t)row * 1024))[t];
  float s  = v.x + v.y + v.z + v.w;
  float sq = v.x*v.x + v.y*v.y + v.z*v.z + v.w*v.w;
#pragma unroll
  for (int mk = 32; mk >= 1; mk >>= 1) {
    s  += __shfl_xor(s,  mk);
    sq += __shfl_xor(sq, mk);
  }
  const int wv = t >> 6;
  if ((t & 63) == 0) { red[wv] = s; red[4 + wv] = sq; }
  __syncthreads();
  s  = red[0] + red[1] + red[2] + red[3];
  sq = red[4] + red[5] + red[6] + red[7];
  const float mu = s * (1.f/1024.f);
  const float rs = rsqrtf(sq * (1.f/1024.f) - mu*mu + 1e-5f);
  const float4 gv = ((const float4*)g)[t];
  const float4 bv = ((const float4*)bta)[t];
  ushort4 o;
  o.x = f2bf((v.x - mu) * rs * gv.x + bv.x);
  o.y = f2bf((v.y - mu) * rs * gv.y + bv.y);
  o.z = f2bf((v.z - mu) * rs * gv.z + bv.z);
  o.w = f2bf((v.w - mu) * rs * gv.w + bv.w);
  ((ushort4*)(h + (size_t)row * 1024))[t] = o;
}

// ---------------------------------------------------------------------------
// bf16 GEMM, m97 structure: C[M,N] = A[M,K] @ Bt[N,K]^T.
// 128x128 tile, BK=32, 256 threads (4 waves 2x2), wave tile 64x64, acc 4x4.
// EPI: 0 = QKV scatter (z selects Wq/Wk/Wv; q scaled 0.125; v transposed)
//      1 = residual: xio[r,c] += acc + bias[c]
//      2 = relu(acc + bias) -> bf16 o0
//      3 = acc + bias -> f32 xio
//      4 = split-K partial: z = K-chunk index, chunk len Kc; part[z][r][c] = acc
template<int EPI>
__global__ __launch_bounds__(256)
void gemm_k(const unsigned short* __restrict__ A,
            const unsigned short* __restrict__ B0,
            const unsigned short* __restrict__ B1,
            const unsigned short* __restrict__ B2,
            const float* __restrict__ bias,
            float* __restrict__ xio,
            unsigned short* __restrict__ o0,
            unsigned short* __restrict__ o1,
            unsigned short* __restrict__ o2,
            int K, int N, int Kc, float* __restrict__ part)
{
  __shared__ __align__(16) unsigned short As[128 * 32];
  __shared__ __align__(16) unsigned short Bs[128 * 32];
  const int tid = threadIdx.x;
  const int wave = tid >> 6, lane = tid & 63;
  const int wm = wave >> 1, wn = wave & 1;
  const int m0 = blockIdx.x * 128, n0 = blockIdx.y * 128;
  const int r16 = lane & 15, r4 = lane >> 4;

  const unsigned short* Bt = B0;
  if (EPI == 0) Bt = (blockIdx.z == 0) ? B0 : (blockIdx.z == 1) ? B1 : B2;
  const int koff = (EPI == 4) ? blockIdx.z * Kc : 0;
  const int klen = (EPI == 4) ? Kc : K;

  // staging: thread t covers row tid>>2 (0..63), 8-short chunk tid&3
  const unsigned short* ga = A  + (size_t)(m0 + (tid >> 2)) * K + koff + (tid & 3) * 8;
  const unsigned short* gb = Bt + (size_t)(n0 + (tid >> 2)) * K + koff + (tid & 3) * 8;
  const size_t rstep = (size_t)64 * K;
  unsigned short* la = As + wave * 512;   // wave-uniform base, 16 rows/wave
  unsigned short* lb = Bs + wave * 512;

  f32x4 acc[4][4] = {};

  for (int kt = 0; kt < klen; kt += 32) {
    __syncthreads();                      // prev tile LDS reads done
    gll16(ga,         la);
    gll16(ga + rstep, la + 2048);
    gll16(gb,         lb);
    gll16(gb + rstep, lb + 2048);
    ga += 32; gb += 32;
    __syncthreads();                      // drains vmcnt -> staging visible
    bf16x8 av[4], bv[4];
#pragma unroll
    for (int mf = 0; mf < 4; mf++)
      av[mf] = *(const bf16x8*)&As[(wm*64 + mf*16 + r16) * 32 + r4 * 8];
#pragma unroll
    for (int nf = 0; nf < 4; nf++)
      bv[nf] = *(const bf16x8*)&Bs[(wn*64 + nf*16 + r16) * 32 + r4 * 8];
#pragma unroll
    for (int mf = 0; mf < 4; mf++)
#pragma unroll
      for (int nf = 0; nf < 4; nf++)
        acc[mf][nf] = mfma16(av[mf], bv[nf], acc[mf][nf]);
  }

  const int row0 = m0 + wm * 64, col0 = n0 + wn * 64;
  float* po = nullptr;
  if (EPI == 4)
    po = part + (size_t)blockIdx.z * ((size_t)gridDim.x * 128 * N);
#pragma unroll
  for (int mf = 0; mf < 4; mf++) {
#pragma unroll
    for (int nf = 0; nf < 4; nf++) {
#pragma unroll
      for (int jj = 0; jj < 4; jj++) {
        const int r = row0 + mf*16 + r4*4 + jj;
        const int c = col0 + nf*16 + r16;
        const float v = acc[mf][nf][jj];
        if (EPI == 0) {
          const int z = blockIdx.z;
          const int b_ = r >> 10, s_ = r & 1023;
          const int hh = c >> 6, e = c & 63;
          if (z == 0)
            o0[((size_t)(b_*16 + hh) * 1024 + s_) * 64 + e] = f2bf(v * 0.125f);
          else if (z == 1)
            o1[((size_t)(b_*16 + hh) * 1024 + s_) * 64 + e] = f2bf(v);
          else
            o2[((size_t)(b_*16 + hh) * 64 + e) * 1024 + s_] = f2bf(v);
        } else if (EPI == 1) {
          const size_t idx = (size_t)r * N + c;
          xio[idx] += v + bias[c];
        } else if (EPI == 2) {
          const float t = v + bias[c];
          o0[(size_t)r * N + c] = f2bf(t > 0.f ? t : 0.f);
        } else if (EPI == 3) {
          xio[(size_t)r * N + c] = v + bias[c];
        } else {
          po[(size_t)r * N + c] = v;
        }
      }
    }
  }
}

// ---------------------------------------------------------------------------
// Split-K reduce: sum KZ partials (stride n4 float4s), add bias.
// RES=1: xio += sum ; RES=0: outw = sum. n4 = M*N/4, nm4 = N/4-1 (N pow2).
template<int RES>
__global__ __launch_bounds__(256)
void red_k(const float* __restrict__ part, const float* __restrict__ bias,
           float* __restrict__ xio, float* __restrict__ outw,
           int n4, int nm4, int KZ)
{
  const float4* p4 = (const float4*)part;
  const float4* b4 = (const float4*)bias;
  for (size_t i = (size_t)blockIdx.x * 256 + threadIdx.x; i < (size_t)n4;
       i += (size_t)gridDim.x * 256) {
    float4 s = p4[i];
    for (int kz = 1; kz < KZ; kz++) {
      float4 t = p4[i + (size_t)kz * n4];
      s.x += t.x; s.y += t.y; s.z += t.z; s.w += t.w;
    }
    float4 bv = b4[i & nm4];
    s.x += bv.x; s.y += bv.y; s.z += bv.z; s.w += bv.w;
    if (RES) {
      float4 xv = ((const float4*)xio)[i];
      s.x += xv.x; s.y += xv.y; s.z += xv.z; s.w += xv.w;
      ((float4*)xio)[i] = s;
    } else {
      ((float4*)outw)[i] = s;
    }
  }
}

// ---------------------------------------------------------------------------
// Flash attention. Grid (8 q-tiles, 16 heads, 4 batch), 256 threads (4 waves).
// q: [B,H,S,64] bf16 (pre-scaled by 0.125), k: [B,H,S,64], vT: [B,H,64,S].
// Each wave owns 32 q rows; KV tiles of 64; online softmax; out att [B*S, D].
__global__ __launch_bounds__(256)
void attn_k(const unsigned short* __restrict__ qb,
            const unsigned short* __restrict__ kb,
            const unsigned short* __restrict__ vtb,
            unsigned short* __restrict__ att)
{
  __shared__ __align__(16) unsigned short Ks[64 * 64];   // [kv][e]
  __shared__ __align__(16) unsigned short Vs[64 * 64];   // [e][kv]
  __shared__ __align__(16) unsigned short Ps[128 * 64];  // [q_local][kv]
  const int qt = blockIdx.x, h = blockIdx.y, b = blockIdx.z;
  const int tid = threadIdx.x, wave = tid >> 6, lane = tid & 63;
  const int r16 = lane & 15, r4 = lane >> 4;
  const int q0 = qt * 128;
  const size_t bh = (size_t)(b * 16 + h);
  const unsigned short* qbh = qb  + bh * 1024 * 64;
  const unsigned short* kbh = kb  + bh * 1024 * 64;
  const unsigned short* vbh = vtb + bh * 64 * 1024;

  bf16x8 qf[2][2];
#pragma unroll
  for (int mf = 0; mf < 2; mf++)
#pragma unroll
    for (int kc = 0; kc < 2; kc++)
      qf[mf][kc] = *(const bf16x8*)&qbh[(size_t)(q0 + wave*32 + mf*16 + r16) * 64 + kc*32 + r4*8];

  f32x4 oacc[2][4] = {};
  float m_i[2][4], l_i[2][4];
#pragma unroll
  for (int mf = 0; mf < 2; mf++)
#pragma unroll
    for (int jj = 0; jj < 4; jj++) { m_i[mf][jj] = -INFINITY; l_i[mf][jj] = 0.f; }

  const int ntiles = q0 / 64 + 2;   // kv tiles covering kv <= q0+127
  for (int t = 0; t < ntiles; t++) {
    const int kv0 = t * 64;
    __syncthreads();                // prev tile reads done
#pragma unroll
    for (int cc = 0; cc < 2; cc++) {
      const int chunk = wave * 2 + cc;
      gll16(kbh + (size_t)(kv0 + chunk*8 + (lane >> 3)) * 64 + (lane & 7) * 8,
            Ks + chunk * 512);
      gll16(vbh + (size_t)(chunk*8 + (lane >> 3)) * 1024 + kv0 + (lane & 7) * 8,
            Vs + chunk * 512);
    }
    __syncthreads();                // staging complete

    // QK^T
    f32x4 sacc[2][4] = {};
#pragma unroll
    for (int kc = 0; kc < 2; kc++) {
#pragma unroll
      for (int nf = 0; nf < 4; nf++) {
        bf16x8 kf = *(const bf16x8*)&Ks[(nf*16 + r16) * 64 + kc*32 + r4*8];
#pragma unroll
        for (int mf = 0; mf < 2; mf++)
          sacc[mf][nf] = mfma16(qf[mf][kc], kf, sacc[mf][nf]);
      }
    }

    // online softmax (per row = (mf, jj); cols spread over 16-lane group x 4 nf)
#pragma unroll
    for (int mf = 0; mf < 2; mf++) {
#pragma unroll
      for (int jj = 0; jj < 4; jj++) {
        const int qrow = q0 + wave*32 + mf*16 + r4*4 + jj;
        float vv[4];
#pragma unroll
        for (int nf = 0; nf < 4; nf++) {
          const int col = kv0 + nf*16 + r16;
          vv[nf] = (col <= qrow) ? sacc[mf][nf][jj] : -1e30f;
        }
        float rmax = fmaxf(fmaxf(vv[0], vv[1]), fmaxf(vv[2], vv[3]));
#pragma unroll
        for (int mk = 8; mk >= 1; mk >>= 1) rmax = fmaxf(rmax, __shfl_xor(rmax, mk));
        const float mnew = fmaxf(m_i[mf][jj], rmax);
        const float corr = __expf(m_i[mf][jj] - mnew);   // first tile: exp(-inf)=0
        float pv[4], ps = 0.f;
#pragma unroll
        for (int nf = 0; nf < 4; nf++) { pv[nf] = __expf(vv[nf] - mnew); ps += pv[nf]; }
#pragma unroll
        for (int mk = 8; mk >= 1; mk >>= 1) ps += __shfl_xor(ps, mk);
        l_i[mf][jj] = l_i[mf][jj] * corr + ps;
        m_i[mf][jj] = mnew;
#pragma unroll
        for (int nh = 0; nh < 4; nh++) oacc[mf][nh][jj] *= corr;
#pragma unroll
        for (int nf = 0; nf < 4; nf++)
          Ps[(wave*32 + mf*16 + r4*4 + jj) * 64 + nf*16 + r16] = f2bf(pv[nf]);
      }
    }
    __syncthreads();                // P visible (safety)

    // PV
#pragma unroll
    for (int kc = 0; kc < 2; kc++) {
#pragma unroll
      for (int mf = 0; mf < 2; mf++) {
        bf16x8 pf = *(const bf16x8*)&Ps[(wave*32 + mf*16 + r16) * 64 + kc*32 + r4*8];
#pragma unroll
        for (int nh = 0; nh < 4; nh++) {
          bf16x8 vf = *(const bf16x8*)&Vs[(nh*16 + r16) * 64 + kc*32 + r4*8];
          oacc[mf][nh] = mfma16(pf, vf, oacc[mf][nh]);
        }
      }
    }
  }

  // finalize + write att [B*S, D], col = h*64 + e
#pragma unroll
  for (int mf = 0; mf < 2; mf++) {
#pragma unroll
    for (int nh = 0; nh < 4; nh++) {
#pragma unroll
      for (int jj = 0; jj < 4; jj++) {
        const int row = q0 + wave*32 + mf*16 + r4*4 + jj;
        const int col = nh*16 + r16;
        const float o = oacc[mf][nh][jj] / l_i[mf][jj];
        att[(size_t)(b * 1024 + row) * 1024 + h*64 + col] = f2bf(o);
      }
    }
  }
}

// ---------------------------------------------------------------------------
extern "C" void kernel_launch(void* const* d_in, const int* in_sizes, int n_in,
                              void* d_out, int out_size, void* d_ws, size_t ws_size,
                              hipStream_t stream)
{
  const int*   toks    = (const int*)  d_in[0];
  const float* tok_emb = (const float*)d_in[1];
  const float* pos_emb = (const float*)d_in[2];
  const float* Wq      = (const float*)d_in[3];
  const float* Wk      = (const float*)d_in[4];
  const float* Wv      = (const float*)d_in[5];
  const float* Wo      = (const float*)d_in[6];
  const float* bo      = (const float*)d_in[7];
  const float* ln1_g   = (const float*)d_in[8];
  const float* ln1_b   = (const float*)d_in[9];
  const float* ln2_g   = (const float*)d_in[10];
  const float* ln2_b   = (const float*)d_in[11];
  const float* W1      = (const float*)d_in[12];
  const float* b1      = (const float*)d_in[13];
  const float* W2      = (const float*)d_in[14];
  const float* b2      = (const float*)d_in[15];
  const float* lnf_g   = (const float*)d_in[16];
  const float* lnf_b   = (const float*)d_in[17];
  const float* Wout    = (const float*)d_in[18];
  const float* bout    = (const float*)d_in[19];
  float* out = (float*)d_out;

  char* w = (char*)d_ws;
  size_t off = 0;
  auto alloc = [&](size_t bytes) -> void* {
    void* p = w + off; off += (bytes + 255) & ~(size_t)255; return p;
  };
  unsigned short* wqT   = (unsigned short*)alloc(8ull*1024*1024*2);
  unsigned short* wkT   = (unsigned short*)alloc(8ull*1024*1024*2);
  unsigned short* wvT   = (unsigned short*)alloc(8ull*1024*1024*2);
  unsigned short* woT   = (unsigned short*)alloc(8ull*1024*1024*2);
  unsigned short* w1T   = (unsigned short*)alloc(8ull*1024*4096*2);
  unsigned short* w2T   = (unsigned short*)alloc(8ull*4096*1024*2);
  unsigned short* woutT = (unsigned short*)alloc(256ull*1024*2);
  float*          x     = (float*)         alloc(4096ull*1024*4);
  unsigned short* hbuf  = (unsigned short*)alloc(4096ull*1024*2);
  unsigned short* qbuf  = (unsigned short*)alloc(64ull*1024*64*2);
  unsigned short* kbuf  = (unsigned short*)alloc(64ull*1024*64*2);
  unsigned short* vtb   = (unsigned short*)alloc(64ull*1024*64*2);
  unsigned short* att   = (unsigned short*)alloc(4096ull*1024*2);
  unsigned short* ff    = (unsigned short*)alloc(4096ull*4096*2);
  float*          part  = (float*)         alloc(64ull*1024*1024);  // split-K partials
  (void)ws_size; (void)in_sizes; (void)n_in; (void)out_size;

  dim3 tb(32, 8);
  tcvt_k<<<dim3(32, 32, 8),  tb, 0, stream>>>(Wq,   wqT,   1024, 1024);
  tcvt_k<<<dim3(32, 32, 8),  tb, 0, stream>>>(Wk,   wkT,   1024, 1024);
  tcvt_k<<<dim3(32, 32, 8),  tb, 0, stream>>>(Wv,   wvT,   1024, 1024);
  tcvt_k<<<dim3(32, 32, 8),  tb, 0, stream>>>(Wo,   woT,   1024, 1024);
  tcvt_k<<<dim3(128, 32, 8), tb, 0, stream>>>(W1,   w1T,   1024, 4096);
  tcvt_k<<<dim3(32, 128, 8), tb, 0, stream>>>(W2,   w2T,   4096, 1024);
  tcvt_k<<<dim3(8, 32, 1),   tb, 0, stream>>>(Wout, woutT, 1024, 256);

  embed_k<<<4096, 256, 0, stream>>>(toks, tok_emb, pos_emb, x);

  for (int l = 0; l < 8; l++) {
    ln_k<<<4096, 256, 0, stream>>>(x, ln1_g + l*1024, ln1_b + l*1024, hbuf);
    gemm_k<0><<<dim3(32, 8, 3), 256, 0, stream>>>(hbuf,
        wqT + (size_t)l*1048576, wkT + (size_t)l*1048576, wvT + (size_t)l*1048576,
        nullptr, nullptr, qbuf, kbuf, vtb, 1024, 1024, 1024, nullptr);
    attn_k<<<dim3(8, 16, 4), 256, 0, stream>>>(qbuf, kbuf, vtb, att);
    // Wo projection: split-K x4 (Kc=256), then residual-reduce into x
    gemm_k<4><<<dim3(32, 8, 4), 256, 0, stream>>>(att,
        woT + (size_t)l*1048576, nullptr, nullptr,
        nullptr, nullptr, nullptr, nullptr, nullptr, 1024, 1024, 256, part);
    red_k<1><<<2048, 256, 0, stream>>>(part, bo + l*1024, x, nullptr,
        1048576, 255, 4);
    ln_k<<<4096, 256, 0, stream>>>(x, ln2_g + l*1024, ln2_b + l*1024, hbuf);
    gemm_k<2><<<dim3(32, 32), 256, 0, stream>>>(hbuf,
        w1T + (size_t)l*4194304, nullptr, nullptr,
        b1 + l*4096, nullptr, ff, nullptr, nullptr, 1024, 4096, 1024, nullptr);
    // FFN2: split-K x4 (Kc=1024), then residual-reduce into x
    gemm_k<4><<<dim3(32, 8, 4), 256, 0, stream>>>(ff,
        w2T + (size_t)l*4194304, nullptr, nullptr,
        nullptr, nullptr, nullptr, nullptr, nullptr, 4096, 1024, 1024, part);
    red_k<1><<<2048, 256, 0, stream>>>(part, b2 + l*1024, x, nullptr,
        1048576, 255, 4);
  }

  ln_k<<<4096, 256, 0, stream>>>(x, lnf_g, lnf_b, hbuf);
  // logits: split-K x8 (Kc=128), then bias-reduce into out
  gemm_k<4><<<dim3(32, 2, 8), 256, 0, stream>>>(hbuf, woutT, nullptr, nullptr,
      nullptr, nullptr, nullptr, nullptr, nullptr, 1024, 256, 128, part);
  red_k<0><<<1024, 256, 0, stream>>>(part, bout, nullptr, out,
      262144, 63, 8);
}

// Round 4
// 2526.989 us; speedup vs baseline: 1.1602x; 1.0105x over previous
//
#include <hip/hip_runtime.h>

#define DEV __device__ __forceinline__

typedef __bf16 bf16x8 __attribute__((ext_vector_type(8)));
typedef float  f32x4  __attribute__((ext_vector_type(4)));

typedef const __attribute__((address_space(1))) unsigned int* gas_ptr;
typedef       __attribute__((address_space(3))) unsigned int* las_ptr;

DEV unsigned short f2bf(float f) {
  union { __bf16 h; unsigned short u; } c; c.h = (__bf16)f; return c.u;
}

DEV void gll16(const void* g, void* l) {
  __builtin_amdgcn_global_load_lds((gas_ptr)g, (las_ptr)l, 16, 0, 0);
}

DEV f32x4 mfma16(bf16x8 a, bf16x8 b, f32x4 c) {
  return __builtin_amdgcn_mfma_f32_16x16x32_bf16(a, b, c, 0, 0, 0);
}

// ---------------------------------------------------------------------------
// Transpose + f32->bf16 convert: src [K,N] f32 -> dst [N,K] bf16. grid.z = layer.
__global__ __launch_bounds__(256)
void tcvt_k(const float* __restrict__ src, unsigned short* __restrict__ dst,
            int K, int N)
{
  __shared__ float t[32][33];
  const int tx = threadIdx.x, ty = threadIdx.y;
  const size_t mo = (size_t)blockIdx.z * K * N;
  const int n0 = blockIdx.x * 32, k0 = blockIdx.y * 32;
  const float* s = src + mo;
  unsigned short* d = dst + mo;
#pragma unroll
  for (int i = 0; i < 4; i++)
    t[ty + i*8][tx] = s[(size_t)(k0 + ty + i*8) * N + n0 + tx];
  __syncthreads();
#pragma unroll
  for (int i = 0; i < 4; i++)
    d[(size_t)(n0 + ty + i*8) * K + k0 + tx] = f2bf(t[tx][ty + i*8]);
}

// ---------------------------------------------------------------------------
// Embedding: x[row] = tok_emb[tok[row]] + pos_emb[row % 1024]
__global__ __launch_bounds__(256)
void embed_k(const int* __restrict__ toks, const float* __restrict__ te,
             const float* __restrict__ pe, float* __restrict__ x)
{
  const int row = blockIdx.x, t = threadIdx.x;
  const int tok = toks[row], s = row & 1023;
  float4 a = ((const float4*)(te + (size_t)tok * 1024))[t];
  float4 p = ((const float4*)(pe + (size_t)s   * 1024))[t];
  float4 o; o.x = a.x+p.x; o.y = a.y+p.y; o.z = a.z+p.z; o.w = a.w+p.w;
  ((float4*)(x + (size_t)row * 1024))[t] = o;
}

// ---------------------------------------------------------------------------
// LayerNorm over D=1024, f32 in -> bf16 out. One block (256 thr) per row.
__global__ __launch_bounds__(256)
void ln_k(const float* __restrict__ x, const float* __restrict__ g,
          const float* __restrict__ bta, unsigned short* __restrict__ h)
{
  __shared__ float red[8];
  const int row = blockIdx.x, t = threadIdx.x;
  const float4 v = ((const float4*)(x + (size_t)row * 1024))[t];
  float s  = v.x + v.y + v.z + v.w;
  float sq = v.x*v.x + v.y*v.y + v.z*v.z + v.w*v.w;
#pragma unroll
  for (int mk = 32; mk >= 1; mk >>= 1) {
    s  += __shfl_xor(s,  mk);
    sq += __shfl_xor(sq, mk);
  }
  const int wv = t >> 6;
  if ((t & 63) == 0) { red[wv] = s; red[4 + wv] = sq; }
  __syncthreads();
  s  = red[0] + red[1] + red[2] + red[3];
  sq = red[4] + red[5] + red[6] + red[7];
  const float mu = s * (1.f/1024.f);
  const float rs = rsqrtf(sq * (1.f/1024.f) - mu*mu + 1e-5f);
  const float4 gv = ((const float4*)g)[t];
  const float4 bv = ((const float4*)bta)[t];
  ushort4 o;
  o.x = f2bf((v.x - mu) * rs * gv.x + bv.x);
  o.y = f2bf((v.y - mu) * rs * gv.y + bv.y);
  o.z = f2bf((v.z - mu) * rs * gv.z + bv.z);
  o.w = f2bf((v.w - mu) * rs * gv.w + bv.w);
  ((ushort4*)(h + (size_t)row * 1024))[t] = o;
}

// ---------------------------------------------------------------------------
// bf16 GEMM, m97 structure: C[M,N] = A[M,K] @ Bt[N,K]^T.
// 128x128 tile, BK=32, 256 threads (4 waves 2x2), wave tile 64x64, acc 4x4.
// EPI: 0 = QKV scatter (z selects Wq/Wk/Wv; q scaled 0.125; v transposed)
//      1 = residual: xio[r,c] += acc + bias[c]
//      2 = relu(acc + bias) -> bf16 o0
//      3 = acc + bias -> f32 xio
//      4 = split-K partial: z = K-chunk index, chunk len Kc; part[z][r][c] = acc
template<int EPI>
__global__ __launch_bounds__(256)
void gemm_k(const unsigned short* __restrict__ A,
            const unsigned short* __restrict__ B0,
            const unsigned short* __restrict__ B1,
            const unsigned short* __restrict__ B2,
            const float* __restrict__ bias,
            float* __restrict__ xio,
            unsigned short* __restrict__ o0,
            unsigned short* __restrict__ o1,
            unsigned short* __restrict__ o2,
            int K, int N, int Kc, float* __restrict__ part)
{
  __shared__ __align__(16) unsigned short As[128 * 32];
  __shared__ __align__(16) unsigned short Bs[128 * 32];
  const int tid = threadIdx.x;
  const int wave = tid >> 6, lane = tid & 63;
  const int wm = wave >> 1, wn = wave & 1;
  const int m0 = blockIdx.x * 128, n0 = blockIdx.y * 128;
  const int r16 = lane & 15, r4 = lane >> 4;

  const unsigned short* Bt = B0;
  if (EPI == 0) Bt = (blockIdx.z == 0) ? B0 : (blockIdx.z == 1) ? B1 : B2;
  const int koff = (EPI == 4) ? blockIdx.z * Kc : 0;
  const int klen = (EPI == 4) ? Kc : K;

  // staging: thread t covers row tid>>2 (0..63), 8-short chunk tid&3
  const unsigned short* ga = A  + (size_t)(m0 + (tid >> 2)) * K + koff + (tid & 3) * 8;
  const unsigned short* gb = Bt + (size_t)(n0 + (tid >> 2)) * K + koff + (tid & 3) * 8;
  const size_t rstep = (size_t)64 * K;
  unsigned short* la = As + wave * 512;   // wave-uniform base, 16 rows/wave
  unsigned short* lb = Bs + wave * 512;

  f32x4 acc[4][4] = {};

  for (int kt = 0; kt < klen; kt += 32) {
    __syncthreads();                      // prev tile LDS reads done
    gll16(ga,         la);
    gll16(ga + rstep, la + 2048);
    gll16(gb,         lb);
    gll16(gb + rstep, lb + 2048);
    ga += 32; gb += 32;
    __syncthreads();                      // drains vmcnt -> staging visible
    bf16x8 av[4], bv[4];
#pragma unroll
    for (int mf = 0; mf < 4; mf++)
      av[mf] = *(const bf16x8*)&As[(wm*64 + mf*16 + r16) * 32 + r4 * 8];
#pragma unroll
    for (int nf = 0; nf < 4; nf++)
      bv[nf] = *(const bf16x8*)&Bs[(wn*64 + nf*16 + r16) * 32 + r4 * 8];
#pragma unroll
    for (int mf = 0; mf < 4; mf++)
#pragma unroll
      for (int nf = 0; nf < 4; nf++)
        acc[mf][nf] = mfma16(av[mf], bv[nf], acc[mf][nf]);
  }

  const int row0 = m0 + wm * 64, col0 = n0 + wn * 64;
  float* po = nullptr;
  if (EPI == 4)
    po = part + (size_t)blockIdx.z * ((size_t)gridDim.x * 128 * N);
#pragma unroll
  for (int mf = 0; mf < 4; mf++) {
#pragma unroll
    for (int nf = 0; nf < 4; nf++) {
#pragma unroll
      for (int jj = 0; jj < 4; jj++) {
        const int r = row0 + mf*16 + r4*4 + jj;
        const int c = col0 + nf*16 + r16;
        const float v = acc[mf][nf][jj];
        if (EPI == 0) {
          const int z = blockIdx.z;
          const int b_ = r >> 10, s_ = r & 1023;
          const int hh = c >> 6, e = c & 63;
          if (z == 0)
            o0[((size_t)(b_*16 + hh) * 1024 + s_) * 64 + e] = f2bf(v * 0.125f);
          else if (z == 1)
            o1[((size_t)(b_*16 + hh) * 1024 + s_) * 64 + e] = f2bf(v);
          else
            o2[((size_t)(b_*16 + hh) * 64 + e) * 1024 + s_] = f2bf(v);
        } else if (EPI == 1) {
          const size_t idx = (size_t)r * N + c;
          xio[idx] += v + bias[c];
        } else if (EPI == 2) {
          const float t = v + bias[c];
          o0[(size_t)r * N + c] = f2bf(t > 0.f ? t : 0.f);
        } else if (EPI == 3) {
          xio[(size_t)r * N + c] = v + bias[c];
        } else {
          po[(size_t)r * N + c] = v;
        }
      }
    }
  }
}

// ---------------------------------------------------------------------------
// Split-K reduce: sum KZ partials (stride n4 float4s), add bias.
// RES=1: xio += sum ; RES=0: outw = sum. n4 = M*N/4, nm4 = N/4-1 (N pow2).
template<int RES>
__global__ __launch_bounds__(256)
void red_k(const float* __restrict__ part, const float* __restrict__ bias,
           float* __restrict__ xio, float* __restrict__ outw,
           int n4, int nm4, int KZ)
{
  const float4* p4 = (const float4*)part;
  const float4* b4 = (const float4*)bias;
  for (size_t i = (size_t)blockIdx.x * 256 + threadIdx.x; i < (size_t)n4;
       i += (size_t)gridDim.x * 256) {
    float4 s = p4[i];
    for (int kz = 1; kz < KZ; kz++) {
      float4 t = p4[i + (size_t)kz * n4];
      s.x += t.x; s.y += t.y; s.z += t.z; s.w += t.w;
    }
    float4 bv = b4[i & nm4];
    s.x += bv.x; s.y += bv.y; s.z += bv.z; s.w += bv.w;
    if (RES) {
      float4 xv = ((const float4*)xio)[i];
      s.x += xv.x; s.y += xv.y; s.z += xv.z; s.w += xv.w;
      ((float4*)xio)[i] = s;
    } else {
      ((float4*)outw)[i] = s;
    }
  }
}

// ---------------------------------------------------------------------------
// Flash attention, latency-optimized. Grid (16 q-tiles, 16 heads, 4 batch),
// 256 threads (4 waves), QBLK=64 (16 q-rows/wave), KVBLK=64.
// Double-buffered KV staging: one barrier per tile; next tile's
// global_load_lds issued right after the barrier so its latency hides under
// this tile's compute. Ps is wave-private (no barrier before PV).
// q: [B,H,S,64] bf16 (pre-scaled by 0.125), k: [B,H,S,64], vT: [B,H,64,S].
__global__ __launch_bounds__(256)
void attn_k(const unsigned short* __restrict__ qb,
            const unsigned short* __restrict__ kb,
            const unsigned short* __restrict__ vtb,
            unsigned short* __restrict__ att)
{
  __shared__ __align__(16) unsigned short Ks[2][64 * 64];  // [buf][kv][e]
  __shared__ __align__(16) unsigned short Vs[2][64 * 64];  // [buf][e][kv]
  __shared__ __align__(16) unsigned short Ps[64 * 72];     // [q_local][kv], pad 72
  const int qt = 15 - blockIdx.x, h = blockIdx.y, b = blockIdx.z;
  const int tid = threadIdx.x, wave = tid >> 6, lane = tid & 63;
  const int r16 = lane & 15, r4 = lane >> 4;
  const int q0 = qt * 64;
  const size_t bh = (size_t)(b * 16 + h);
  const unsigned short* qbh = qb  + bh * 1024 * 64;
  const unsigned short* kbh = kb  + bh * 1024 * 64;
  const unsigned short* vbh = vtb + bh * 64 * 1024;

  // Q fragments for this wave's 16 rows
  bf16x8 qf[2];
#pragma unroll
  for (int kc = 0; kc < 2; kc++)
    qf[kc] = *(const bf16x8*)&qbh[(size_t)(q0 + wave*16 + r16) * 64 + kc*32 + r4*8];

  f32x4 oacc[4] = {};
  float m_i[4], l_i[4];
#pragma unroll
  for (int jj = 0; jj < 4; jj++) { m_i[jj] = -1e30f; l_i[jj] = 0.f; }

  const int nt = qt + 1;   // kv tiles 0..qt (diag = qt)

  // stage tile 0 into buffer 0
#pragma unroll
  for (int cc = 0; cc < 2; cc++) {
    const int chunk = wave * 2 + cc;
    gll16(kbh + (size_t)(chunk*8 + (lane >> 3)) * 64 + (lane & 7) * 8,
          &Ks[0][chunk * 512]);
    gll16(vbh + (size_t)(chunk*8 + (lane >> 3)) * 1024 + (lane & 7) * 8,
          &Vs[0][chunk * 512]);
  }

  int cur = 0;
  for (int t = 0; t < nt; t++) {
    __syncthreads();   // drains vmcnt: buf[cur] staged; all waves done with buf[cur^1]
    if (t + 1 < nt) {  // prefetch next tile into the other buffer
      const int kv1 = (t + 1) * 64;
#pragma unroll
      for (int cc = 0; cc < 2; cc++) {
        const int chunk = wave * 2 + cc;
        gll16(kbh + (size_t)(kv1 + chunk*8 + (lane >> 3)) * 64 + (lane & 7) * 8,
              &Ks[cur ^ 1][chunk * 512]);
        gll16(vbh + (size_t)(chunk*8 + (lane >> 3)) * 1024 + kv1 + (lane & 7) * 8,
              &Vs[cur ^ 1][chunk * 512]);
      }
    }

    // QK^T: sacc[nf] over this wave's 16 rows x 64 kv cols
    f32x4 sacc[4] = {};
#pragma unroll
    for (int kc = 0; kc < 2; kc++)
#pragma unroll
      for (int nf = 0; nf < 4; nf++) {
        bf16x8 kf = *(const bf16x8*)&Ks[cur][(nf*16 + r16) * 64 + kc*32 + r4*8];
        sacc[nf] = mfma16(qf[kc], kf, sacc[nf]);
      }

    const bool diag = (t == nt - 1);
#pragma unroll
    for (int jj = 0; jj < 4; jj++) {
      float vv[4];
#pragma unroll
      for (int nf = 0; nf < 4; nf++) vv[nf] = sacc[nf][jj];
      if (diag) {
        const int qrow_l = wave*16 + r4*4 + jj;   // kv0 == q0 on diag tile
#pragma unroll
        for (int nf = 0; nf < 4; nf++)
          if (nf*16 + r16 > qrow_l) vv[nf] = -1e30f;
      }
      float rmax = fmaxf(fmaxf(vv[0], vv[1]), fmaxf(vv[2], vv[3]));
#pragma unroll
      for (int mk = 8; mk >= 1; mk >>= 1) rmax = fmaxf(rmax, __shfl_xor(rmax, mk));
      const float mnew = fmaxf(m_i[jj], rmax);
      const float corr = __expf(m_i[jj] - mnew);
      m_i[jj] = mnew;
      float p0 = __expf(vv[0] - mnew), p1 = __expf(vv[1] - mnew);
      float p2 = __expf(vv[2] - mnew), p3 = __expf(vv[3] - mnew);
      l_i[jj] = l_i[jj] * corr + ((p0 + p1) + (p2 + p3));   // lane-partial l
#pragma unroll
      for (int nh = 0; nh < 4; nh++) oacc[nh][jj] *= corr;
      const int prow = (wave*16 + r4*4 + jj) * 72;
      Ps[prow + r16     ] = f2bf(p0);
      Ps[prow + 16 + r16] = f2bf(p1);
      Ps[prow + 32 + r16] = f2bf(p2);
      Ps[prow + 48 + r16] = f2bf(p3);
    }

    // PV (Ps rows are wave-private: no barrier needed)
#pragma unroll
    for (int kc = 0; kc < 2; kc++) {
      bf16x8 pf = *(const bf16x8*)&Ps[(wave*16 + r16) * 72 + kc*32 + r4*8];
#pragma unroll
      for (int nh = 0; nh < 4; nh++) {
        bf16x8 vf = *(const bf16x8*)&Vs[cur][(nh*16 + r16) * 64 + kc*32 + r4*8];
        oacc[nh] = mfma16(pf, vf, oacc[nh]);
      }
    }
    cur ^= 1;
  }

  // reduce lane-partial l over the 16-lane row group
#pragma unroll
  for (int jj = 0; jj < 4; jj++)
#pragma unroll
    for (int mk = 8; mk >= 1; mk >>= 1) l_i[jj] += __shfl_xor(l_i[jj], mk);

  // write att [B*S, D], col = h*64 + e
#pragma unroll
  for (int nh = 0; nh < 4; nh++) {
#pragma unroll
    for (int jj = 0; jj < 4; jj++) {
      const int row = q0 + wave*16 + r4*4 + jj;
      const int col = nh*16 + r16;
      const float o = oacc[nh][jj] / l_i[jj];
      att[(size_t)(b * 1024 + row) * 1024 + h*64 + col] = f2bf(o);
    }
  }
}

// ---------------------------------------------------------------------------
extern "C" void kernel_launch(void* const* d_in, const int* in_sizes, int n_in,
                              void* d_out, int out_size, void* d_ws, size_t ws_size,
                              hipStream_t stream)
{
  const int*   toks    = (const int*)  d_in[0];
  const float* tok_emb = (const float*)d_in[1];
  const float* pos_emb = (const float*)d_in[2];
  const float* Wq      = (const float*)d_in[3];
  const float* Wk      = (const float*)d_in[4];
  const float* Wv      = (const float*)d_in[5];
  const float* Wo      = (const float*)d_in[6];
  const float* bo      = (const float*)d_in[7];
  const float* ln1_g   = (const float*)d_in[8];
  const float* ln1_b   = (const float*)d_in[9];
  const float* ln2_g   = (const float*)d_in[10];
  const float* ln2_b   = (const float*)d_in[11];
  const float* W1      = (const float*)d_in[12];
  const float* b1      = (const float*)d_in[13];
  const float* W2      = (const float*)d_in[14];
  const float* b2      = (const float*)d_in[15];
  const float* lnf_g   = (const float*)d_in[16];
  const float* lnf_b   = (const float*)d_in[17];
  const float* Wout    = (const float*)d_in[18];
  const float* bout    = (const float*)d_in[19];
  float* out = (float*)d_out;

  char* w = (char*)d_ws;
  size_t off = 0;
  auto alloc = [&](size_t bytes) -> void* {
    void* p = w + off; off += (bytes + 255) & ~(size_t)255; return p;
  };
  unsigned short* wqT   = (unsigned short*)alloc(8ull*1024*1024*2);
  unsigned short* wkT   = (unsigned short*)alloc(8ull*1024*1024*2);
  unsigned short* wvT   = (unsigned short*)alloc(8ull*1024*1024*2);
  unsigned short* woT   = (unsigned short*)alloc(8ull*1024*1024*2);
  unsigned short* w1T   = (unsigned short*)alloc(8ull*1024*4096*2);
  unsigned short* w2T   = (unsigned short*)alloc(8ull*4096*1024*2);
  unsigned short* woutT = (unsigned short*)alloc(256ull*1024*2);
  float*          x     = (float*)         alloc(4096ull*1024*4);
  unsigned short* hbuf  = (unsigned short*)alloc(4096ull*1024*2);
  unsigned short* qbuf  = (unsigned short*)alloc(64ull*1024*64*2);
  unsigned short* kbuf  = (unsigned short*)alloc(64ull*1024*64*2);
  unsigned short* vtb   = (unsigned short*)alloc(64ull*1024*64*2);
  unsigned short* att   = (unsigned short*)alloc(4096ull*1024*2);
  unsigned short* ff    = (unsigned short*)alloc(4096ull*4096*2);
  float*          part  = (float*)         alloc(64ull*1024*1024);  // split-K partials
  (void)ws_size; (void)in_sizes; (void)n_in; (void)out_size;

  dim3 tb(32, 8);
  tcvt_k<<<dim3(32, 32, 8),  tb, 0, stream>>>(Wq,   wqT,   1024, 1024);
  tcvt_k<<<dim3(32, 32, 8),  tb, 0, stream>>>(Wk,   wkT,   1024, 1024);
  tcvt_k<<<dim3(32, 32, 8),  tb, 0, stream>>>(Wv,   wvT,   1024, 1024);
  tcvt_k<<<dim3(32, 32, 8),  tb, 0, stream>>>(Wo,   woT,   1024, 1024);
  tcvt_k<<<dim3(128, 32, 8), tb, 0, stream>>>(W1,   w1T,   1024, 4096);
  tcvt_k<<<dim3(32, 128, 8), tb, 0, stream>>>(W2,   w2T,   4096, 1024);
  tcvt_k<<<dim3(8, 32, 1),   tb, 0, stream>>>(Wout, woutT, 1024, 256);

  embed_k<<<4096, 256, 0, stream>>>(toks, tok_emb, pos_emb, x);

  for (int l = 0; l < 8; l++) {
    ln_k<<<4096, 256, 0, stream>>>(x, ln1_g + l*1024, ln1_b + l*1024, hbuf);
    gemm_k<0><<<dim3(32, 8, 3), 256, 0, stream>>>(hbuf,
        wqT + (size_t)l*1048576, wkT + (size_t)l*1048576, wvT + (size_t)l*1048576,
        nullptr, nullptr, qbuf, kbuf, vtb, 1024, 1024, 1024, nullptr);
    attn_k<<<dim3(16, 16, 4), 256, 0, stream>>>(qbuf, kbuf, vtb, att);
    // Wo projection: split-K x4 (Kc=256), then residual-reduce into x
    gemm_k<4><<<dim3(32, 8, 4), 256, 0, stream>>>(att,
        woT + (size_t)l*1048576, nullptr, nullptr,
        nullptr, nullptr, nullptr, nullptr, nullptr, 1024, 1024, 256, part);
    red_k<1><<<2048, 256, 0, stream>>>(part, bo + l*1024, x, nullptr,
        1048576, 255, 4);
    ln_k<<<4096, 256, 0, stream>>>(x, ln2_g + l*1024, ln2_b + l*1024, hbuf);
    gemm_k<2><<<dim3(32, 32), 256, 0, stream>>>(hbuf,
        w1T + (size_t)l*4194304, nullptr, nullptr,
        b1 + l*4096, nullptr, ff, nullptr, nullptr, 1024, 4096, 1024, nullptr);
    // FFN2: split-K x4 (Kc=1024), then residual-reduce into x
    gemm_k<4><<<dim3(32, 8, 4), 256, 0, stream>>>(ff,
        w2T + (size_t)l*4194304, nullptr, nullptr,
        nullptr, nullptr, nullptr, nullptr, nullptr, 4096, 1024, 1024, part);
    red_k<1><<<2048, 256, 0, stream>>>(part, b2 + l*1024, x, nullptr,
        1048576, 255, 4);
  }

  ln_k<<<4096, 256, 0, stream>>>(x, lnf_g, lnf_b, hbuf);
  // logits: split-K x8 (Kc=128), then bias-reduce into out
  gemm_k<4><<<dim3(32, 2, 8), 256, 0, stream>>>(hbuf, woutT, nullptr, nullptr,
      nullptr, nullptr, nullptr, nullptr, nullptr, 1024, 256, 128, part);
  red_k<0><<<1024, 256, 0, stream>>>(part, bout, nullptr, out,
      262144, 63, 8);
}